// Round 11
// baseline (255.788 us; speedup 1.0000x reference)
//
#include <hip/hip_runtime.h>

typedef float f32x4 __attribute__((ext_vector_type(4)));
typedef short bf16x8 __attribute__((ext_vector_type(8)));

__device__ __forceinline__ float bf2f(unsigned short h) {
  return __uint_as_float(((unsigned int)h) << 16);
}
__device__ __forceinline__ unsigned short f2bf(float f) {
  unsigned int u = __float_as_uint(f);
  unsigned int r = u + 0x7fffu + ((u >> 16) & 1u);
  return (unsigned short)(r >> 16);
}
__device__ __forceinline__ float fast_exp2(float x) {
  return __builtin_amdgcn_exp2f(x);  // v_exp_f32: D = 2^S0
}
__device__ __forceinline__ unsigned cvt_pk_bf16(float lo, float hi) {
  unsigned d;
  asm("v_cvt_pk_bf16_f32 %0, %1, %2" : "=v"(d) : "v"(lo), "v"(hi));
  return d;
}
__device__ __forceinline__ float max3f(float a, float b, float c) {
  float d;
  asm("v_max3_f32 %0, %1, %2, %3" : "=v"(d) : "v"(a), "v"(b), "v"(c));
  return d;
}

__device__ __forceinline__ void gload_lds16(const void* g, void* l) {
  __builtin_amdgcn_global_load_lds((const __attribute__((address_space(1))) void*)g,
                                   (__attribute__((address_space(3))) void*)l, 16, 0, 0);
}

// XCD-aware bijective block swizzle (T1). Requires nwg % 8 == 0 (all our grids satisfy).
// XCD x (= orig % 8 under round-robin dispatch) gets the contiguous work chunk
// [x*nwg/8, (x+1)*nwg/8) -> neighboring tiles share one XCD's L2.
__device__ __forceinline__ int xcd_swizzle() {
  const int nwg = gridDim.x * gridDim.y;
  const int orig = blockIdx.y * gridDim.x + blockIdx.x;
  const int cpx = nwg >> 3;
  return (orig & 7) * cpx + (orig >> 3);
}

// ---------------- fp32 -> bf16 elementwise convert (vectorized) ----------------
__global__ void conv_bf16(const float* __restrict__ src, unsigned short* __restrict__ dst, int n4) {
  for (int i = blockIdx.x * blockDim.x + threadIdx.x; i < n4; i += gridDim.x * blockDim.x) {
    float4 v = ((const float4*)src)[i];
    ushort4 o;
    o.x = f2bf(v.x); o.y = f2bf(v.y); o.z = f2bf(v.z); o.w = f2bf(v.w);
    ((ushort4*)dst)[i] = o;
  }
}

// ------------- fp32 [R][C] -> bf16 dst[C + dstRowOff][R] transpose-convert -------------
__global__ void tconv(const float* __restrict__ src, unsigned short* __restrict__ dst,
                      int C, int dstRowOff, int dstLD) {
  __shared__ float tile[32][33];
  int c0 = blockIdx.x * 32, r0 = blockIdx.y * 32;
  int tx = threadIdx.x, ty = threadIdx.y;
#pragma unroll
  for (int i = 0; i < 4; ++i)
    tile[ty + i * 8][tx] = src[(size_t)(r0 + ty + i * 8) * C + c0 + tx];
  __syncthreads();
#pragma unroll
  for (int i = 0; i < 4; ++i)
    dst[(size_t)(dstRowOff + c0 + ty + i * 8) * dstLD + r0 + tx] = f2bf(tile[tx][ty + i * 8]);
}

// ---------------- generic GEMM: C[M][N] = A * BT^T (bf16 in, fp32/bf16 out) ----------------
template <typename OutT>
__global__ __launch_bounds__(256) void gemm_bt(const unsigned short* __restrict__ A,
                                               const unsigned short* __restrict__ BT,
                                               OutT* __restrict__ C, int M, int N, int K) {
  __shared__ unsigned short As[128 * 64];
  __shared__ unsigned short Bs[128 * 64];
  const int tid = threadIdx.x;
  const int lane = tid & 63;
  const int wid = tid >> 6;
  const int g = lane >> 4, l15 = lane & 15;
  const int wr = wid >> 1, wc = wid & 1;
  const int swz = xcd_swizzle();
  const int bn = swz % gridDim.x, bm = swz / gridDim.x;
  const unsigned short* Ab = A + (size_t)bm * 128 * K;
  const unsigned short* Bb = BT + (size_t)bn * 128 * K;
  f32x4 acc[4][4] = {};
  int Rj[4], csj[4];
#pragma unroll
  for (int j = 0; j < 4; ++j) {
    int c = j * 256 + tid;
    Rj[j] = c >> 3;
    csj[j] = ((c & 7) ^ (Rj[j] & 7)) * 8;
  }
  for (int k0 = 0; k0 < K; k0 += 64) {
#pragma unroll
    for (int j = 0; j < 4; ++j) {
      gload_lds16(Ab + (size_t)Rj[j] * K + k0 + csj[j], &As[(j * 256 + (wid << 6)) * 8]);
      gload_lds16(Bb + (size_t)Rj[j] * K + k0 + csj[j], &Bs[(j * 256 + (wid << 6)) * 8]);
    }
    __syncthreads();
    bf16x8 af[4][2], bfr[4][2];
#pragma unroll
    for (int i = 0; i < 4; ++i)
#pragma unroll
      for (int kk = 0; kk < 2; ++kk) {
        int rowa = wr * 64 + i * 16 + l15;
        int cha = ((kk * 4 + g) ^ (rowa & 7)) * 8;
        af[i][kk] = *(const bf16x8*)&As[rowa * 64 + cha];
        int rowb = wc * 64 + i * 16 + l15;
        int chb = ((kk * 4 + g) ^ (rowb & 7)) * 8;
        bfr[i][kk] = *(const bf16x8*)&Bs[rowb * 64 + chb];
      }
    __builtin_amdgcn_s_setprio(1);
#pragma unroll
    for (int kk = 0; kk < 2; ++kk)
#pragma unroll
      for (int i = 0; i < 4; ++i)
#pragma unroll
        for (int j = 0; j < 4; ++j)
          acc[i][j] = __builtin_amdgcn_mfma_f32_16x16x32_bf16(af[i][kk], bfr[j][kk], acc[i][j], 0, 0, 0);
    __builtin_amdgcn_s_setprio(0);
    __syncthreads();
  }
  const int rbase = bm * 128 + wr * 64 + ((lane >> 4) << 2);
  const int cbase = bn * 128 + wc * 64 + l15;
#pragma unroll
  for (int i = 0; i < 4; ++i)
#pragma unroll
    for (int j = 0; j < 4; ++j)
#pragma unroll
      for (int r = 0; r < 4; ++r) {
        int row = rbase + i * 16 + r;
        int col = cbase + j * 16;
        if constexpr (sizeof(OutT) == 2)
          C[(size_t)row * N + col] = f2bf(acc[i][j][r]);
        else
          C[(size_t)row * N + col] = acc[i][j][r];
      }
}

// ---------------- GEMM1 with fused RoPE / gate-split epilogue ----------------
// A = hb16 [4096][2048], BT = wcatT [4608][2048]. Cols 0..2047 -> roped q (log2e-scaled,
// head-major); 2048..4095 -> gate buffer; 4096..4607 -> roped k (head-major).
__global__ __launch_bounds__(256) void gemm_qgk(const unsigned short* __restrict__ A,
                                                const unsigned short* __restrict__ BT,
                                                const float* __restrict__ cosT,
                                                const float* __restrict__ sinT,
                                                unsigned short* __restrict__ qrope,
                                                unsigned short* __restrict__ gateb,
                                                unsigned short* __restrict__ krope) {
  const int K = 2048;
  __shared__ unsigned short As[128 * 64];
  __shared__ unsigned short Bs[128 * 64];
  const int tid = threadIdx.x;
  const int lane = tid & 63;
  const int wid = tid >> 6;
  const int g = lane >> 4, l15 = lane & 15;
  const int wr = wid >> 1, wc = wid & 1;
  const int swz = xcd_swizzle();
  const int bn = swz % gridDim.x, bm = swz / gridDim.x;
  const unsigned short* Ab = A + (size_t)bm * 128 * K;
  const unsigned short* Bb = BT + (size_t)bn * 128 * K;
  f32x4 acc[4][4] = {};
  int Rj[4], csj[4];
#pragma unroll
  for (int j = 0; j < 4; ++j) {
    int c = j * 256 + tid;
    Rj[j] = c >> 3;
    csj[j] = ((c & 7) ^ (Rj[j] & 7)) * 8;
  }
  for (int k0 = 0; k0 < K; k0 += 64) {
#pragma unroll
    for (int j = 0; j < 4; ++j) {
      gload_lds16(Ab + (size_t)Rj[j] * K + k0 + csj[j], &As[(j * 256 + (wid << 6)) * 8]);
      gload_lds16(Bb + (size_t)Rj[j] * K + k0 + csj[j], &Bs[(j * 256 + (wid << 6)) * 8]);
    }
    __syncthreads();
    bf16x8 af[4][2], bfr[4][2];
#pragma unroll
    for (int i = 0; i < 4; ++i)
#pragma unroll
      for (int kk = 0; kk < 2; ++kk) {
        int rowa = wr * 64 + i * 16 + l15;
        int cha = ((kk * 4 + g) ^ (rowa & 7)) * 8;
        af[i][kk] = *(const bf16x8*)&As[rowa * 64 + cha];
        int rowb = wc * 64 + i * 16 + l15;
        int chb = ((kk * 4 + g) ^ (rowb & 7)) * 8;
        bfr[i][kk] = *(const bf16x8*)&Bs[rowb * 64 + chb];
      }
    __builtin_amdgcn_s_setprio(1);
#pragma unroll
    for (int kk = 0; kk < 2; ++kk)
#pragma unroll
      for (int i = 0; i < 4; ++i)
#pragma unroll
        for (int j = 0; j < 4; ++j)
          acc[i][j] = __builtin_amdgcn_mfma_f32_16x16x32_bf16(af[i][kk], bfr[j][kk], acc[i][j], 0, 0, 0);
    __builtin_amdgcn_s_setprio(0);
    __syncthreads();
  }
  const int rbase = bm * 128 + wr * 64 + ((lane >> 4) << 2);
  if (bn < 16) {
    const int h = bn * 2 + wc;
#pragma unroll
    for (int i = 0; i < 4; ++i)
#pragma unroll
      for (int j = 0; j < 4; ++j)
#pragma unroll
        for (int r = 0; r < 4; ++r) {
          int row = rbase + i * 16 + r;
          int b = row >> 11, s = row & 2047;
          int d = j * 16 + l15;
          float c = cosT[s * 64 + d], sn = sinT[s * 64 + d];
          float x = acc[i][j][r], xp = acc[i][j ^ 2][r];
          float v = x * c + (((j & 2) == 0) ? -xp : xp) * sn;
          qrope[((size_t)(b * 32 + h) * 2048 + s) * 64 + d] = f2bf(v * 1.44269504089f);
        }
  } else if (bn < 32) {
    const int cb = (bn - 16) * 128 + wc * 64;
#pragma unroll
    for (int i = 0; i < 4; ++i)
#pragma unroll
      for (int j = 0; j < 4; ++j)
#pragma unroll
        for (int r = 0; r < 4; ++r) {
          int row = rbase + i * 16 + r;
          int b = row >> 11, s = row & 2047;
          gateb[(size_t)(b * 2048 + s) * 2048 + cb + j * 16 + l15] = f2bf(acc[i][j][r]);
        }
  } else {
    const int kh = (bn - 32) * 2 + wc;
#pragma unroll
    for (int i = 0; i < 4; ++i)
#pragma unroll
      for (int j = 0; j < 4; ++j)
#pragma unroll
        for (int r = 0; r < 4; ++r) {
          int row = rbase + i * 16 + r;
          int b = row >> 11, s = row & 2047;
          int d = j * 16 + l15;
          float c = cosT[s * 64 + d], sn = sinT[s * 64 + d];
          float x = acc[i][j][r], xp = acc[i][j ^ 2][r];
          float v = x * c + (((j & 2) == 0) ? -xp : xp) * sn;
          krope[((size_t)(b * 8 + kh) * 2048 + s) * 64 + d] = f2bf(v);
        }
  }
}

// ---------------- krope [bh][2048][64] -> kT [bh][64][2048] ----------------
__global__ void ktrans(const unsigned short* __restrict__ krope, unsigned short* __restrict__ kT) {
  __shared__ unsigned short tile[64][65];
  int bh = blockIdx.y;
  int s0 = blockIdx.x * 64;
  const unsigned short* src = krope + (size_t)bh * 2048 * 64;
  unsigned short* dst = kT + (size_t)bh * 64 * 2048;
  int tx = threadIdx.x & 63, ty = threadIdx.x >> 6;
#pragma unroll
  for (int i = 0; i < 16; ++i)
    tile[ty + i * 4][tx] = src[(size_t)(s0 + ty + i * 4) * 64 + tx];
  __syncthreads();
#pragma unroll
  for (int i = 0; i < 16; ++i)
    dst[(size_t)(ty + i * 4) * 2048 + s0 + tx] = tile[tx][ty + i * 4];
}

// ---------------- fused causal flash attention (V == roped K), gated epilogue ----------------
// Round-5 measured structure (92us): Q staged via Ps LDS, grid (bh fastest, qblk=15-y),
// double-buffered K/KT staging, swapped QK^T, exp2+defer-max softmax, single barrier/tile.
// cvt_pk P-write/epilogue + max3 reduction (VALU-only swap, verified rounds 6-10).
__global__ __launch_bounds__(256) void attn_fused(const unsigned short* __restrict__ qrope,
                                                  const unsigned short* __restrict__ krope,
                                                  const unsigned short* __restrict__ kT,
                                                  const unsigned short* __restrict__ gateb,
                                                  unsigned short* __restrict__ attng) {
  __shared__ unsigned short Ks[2][64 * 64];
  __shared__ unsigned short KTs[2][64 * 64];
  __shared__ unsigned short Ps[128 * 64];  // Q staging, then P tiles (wave-private rows)
  const int qblk = 15 - blockIdx.y;       // long blocks dispatched first
  const int bh = blockIdx.x;              // 0..63
  const int b = bh >> 5, h = bh & 31, kh = h >> 2;
  const int q0 = qblk * 128;
  const int tid = threadIdx.x, lane = tid & 63, wid = tid >> 6;
  const int g = lane >> 4, l15 = lane & 15;
  const unsigned short* Qbase = qrope + ((size_t)(b * 32 + h) * 2048 + q0) * 64;
  const unsigned short* Kbase = krope + (size_t)(b * 8 + kh) * 2048 * 64;
  const unsigned short* KTbase = kT + (size_t)(b * 8 + kh) * 64 * 2048;

  // ---- stage Q (16KB) into Ps, swizzled-source / linear-LDS ----
#pragma unroll
  for (int j = 0; j < 4; ++j) {
    int F = ((j * 4 + wid) << 10) + (lane << 4);  // byte offset in tile
    int R = F >> 7;
    int cs = ((F >> 4) & 7) ^ (R & 7);
    gload_lds16(Qbase + (size_t)R * 64 + cs * 8, &Ps[(j * 4 + wid) << 9]);
  }
  // ---- stage K/KT tile 0 into buffer 0 ----
  {
#pragma unroll
    for (int j = 0; j < 2; ++j) {
      int F = ((j * 4 + wid) << 10) + (lane << 4);
      int R = F >> 7;
      int cs = ((F >> 4) & 7) ^ (R & 7);
      gload_lds16(Kbase + (size_t)R * 64 + cs * 8, &Ks[0][(j * 4 + wid) << 9]);
      gload_lds16(KTbase + (size_t)R * 2048 + cs * 8, &KTs[0][(j * 4 + wid) << 9]);
    }
  }
  __syncthreads();

  // ---- Q fragments (swizzled read) ----
  bf16x8 qf[2][2];
#pragma unroll
  for (int i = 0; i < 2; ++i)
#pragma unroll
    for (int ks = 0; ks < 2; ++ks) {
      int row = wid * 32 + i * 16 + l15;
      int ch = (ks * 4 + g) ^ (row & 7);
      qf[i][ks] = *(const bf16x8*)&Ps[row * 64 + ch * 8];
    }
  __syncthreads();  // all waves have Q; Ps reusable

  f32x4 oaccT[2][4] = {};
  float mrow[2] = {-1e30f, -1e30f}, lrow[2] = {0.f, 0.f};

  const int nt = 2 * qblk + 2;
  for (int t = 0; t < nt; ++t) {
    const int cur = t & 1;
    if (t + 1 < nt) {
      const int nb = cur ^ 1;
#pragma unroll
      for (int j = 0; j < 2; ++j) {
        int F = ((j * 4 + wid) << 10) + (lane << 4);
        int R = F >> 7;
        int cs = ((F >> 4) & 7) ^ (R & 7);
        gload_lds16(Kbase + (size_t)((t + 1) * 64 + R) * 64 + cs * 8, &Ks[nb][(j * 4 + wid) << 9]);
        gload_lds16(KTbase + (size_t)R * 2048 + (t + 1) * 64 + cs * 8, &KTs[nb][(j * 4 + wid) << 9]);
      }
    }
    // ---- S^T = K * Q^T  (rows = keys, cols = q); S in log2 units (Q pre-scaled) ----
    f32x4 st[2][4] = {};
#pragma unroll
    for (int ks = 0; ks < 2; ++ks) {
      bf16x8 kf[4];
#pragma unroll
      for (int nf = 0; nf < 4; ++nf) {
        int row = nf * 16 + l15;
        int ch = (ks * 4 + g) ^ (row & 7);
        kf[nf] = *(const bf16x8*)&Ks[cur][row * 64 + ch * 8];
      }
      __builtin_amdgcn_s_setprio(1);
#pragma unroll
      for (int i = 0; i < 2; ++i)
#pragma unroll
        for (int nf = 0; nf < 4; ++nf)
          st[i][nf] = __builtin_amdgcn_mfma_f32_16x16x32_bf16(kf[nf], qf[i][ks], st[i][nf], 0, 0, 0);
      __builtin_amdgcn_s_setprio(0);
    }
    if (t >= 2 * qblk) {
#pragma unroll
      for (int i = 0; i < 2; ++i) {
        int qabs = q0 + wid * 32 + i * 16 + l15;
#pragma unroll
        for (int nf = 0; nf < 4; ++nf)
#pragma unroll
          for (int r = 0; r < 4; ++r) {
            int kabs = t * 64 + nf * 16 + 4 * g + r;
            if (kabs > qabs) st[i][nf][r] += -1e9f;
          }
      }
    }
    // ---- online softmax, exp2 domain, defer-max, max3 tree ----
#pragma unroll
    for (int i = 0; i < 2; ++i) {
      float a0 = max3f(st[i][0][0], st[i][0][1], st[i][0][2]);
      float a1 = max3f(st[i][0][3], st[i][1][0], st[i][1][1]);
      float a2 = max3f(st[i][1][2], st[i][1][3], st[i][2][0]);
      float a3 = max3f(st[i][2][1], st[i][2][2], st[i][2][3]);
      float a4 = max3f(st[i][3][0], st[i][3][1], st[i][3][2]);
      float pm = fmaxf(max3f(a0, a1, a2), max3f(a3, a4, st[i][3][3]));
      pm = fmaxf(pm, __shfl_xor(pm, 16, 64));
      pm = fmaxf(pm, __shfl_xor(pm, 32, 64));
      if (!__all(pm <= mrow[i] + 8.f)) {
        float mnew = fmaxf(mrow[i], pm);
        float scale = fast_exp2(mrow[i] - mnew);
        mrow[i] = mnew;
        lrow[i] *= scale;
#pragma unroll
        for (int df = 0; df < 4; ++df)
#pragma unroll
          for (int r = 0; r < 4; ++r) oaccT[i][df][r] *= scale;
      }
      float rs = 0.f;
#pragma unroll
      for (int nf = 0; nf < 4; ++nf)
#pragma unroll
        for (int r = 0; r < 4; ++r) {
          float p = fast_exp2(st[i][nf][r] - mrow[i]);
          st[i][nf][r] = p;
          rs += p;
        }
      rs += __shfl_xor(rs, 16, 64);
      rs += __shfl_xor(rs, 32, 64);
      lrow[i] += rs;
    }
    // ---- write P rows (wave-private; hw cvt_pk, 8B stores) ----
#pragma unroll
    for (int i = 0; i < 2; ++i) {
      int q = wid * 32 + i * 16 + l15;
#pragma unroll
      for (int nf = 0; nf < 4; ++nf) {
        int k0 = nf * 16 + 4 * g;
        int ch = (k0 >> 3) ^ (q & 7);
        unsigned w0 = cvt_pk_bf16(st[i][nf][0], st[i][nf][1]);
        unsigned w1 = cvt_pk_bf16(st[i][nf][2], st[i][nf][3]);
        *(uint2*)&Ps[q * 64 + ch * 8 + (k0 & 7)] = make_uint2(w0, w1);
      }
    }
    // no barrier: P rows are read only by the writing wave
    // ---- O^T += V^T * P^T  (rows = d, cols = q) ----
#pragma unroll
    for (int ks = 0; ks < 2; ++ks) {
      bf16x8 pf[2], vf[4];
#pragma unroll
      for (int i = 0; i < 2; ++i) {
        int row = wid * 32 + i * 16 + l15;
        int ch = (ks * 4 + g) ^ (row & 7);
        pf[i] = *(const bf16x8*)&Ps[row * 64 + ch * 8];
      }
#pragma unroll
      for (int df = 0; df < 4; ++df) {
        int row = df * 16 + l15;
        int ch = (ks * 4 + g) ^ (row & 7);
        vf[df] = *(const bf16x8*)&KTs[cur][row * 64 + ch * 8];
      }
      __builtin_amdgcn_s_setprio(1);
#pragma unroll
      for (int i = 0; i < 2; ++i)
#pragma unroll
        for (int df = 0; df < 4; ++df)
          oaccT[i][df] = __builtin_amdgcn_mfma_f32_16x16x32_bf16(vf[df], pf[i], oaccT[i][df], 0, 0, 0);
      __builtin_amdgcn_s_setprio(0);
    }
    __syncthreads();  // staging buffers for t+1 may now be overwritten
  }
  // ---- gated epilogue (O^T: lane holds q = lane&15, d = df*16 + 4g + r) ----
#pragma unroll
  for (int i = 0; i < 2; ++i) {
    float rl = 1.f / lrow[i];
    int qabs = q0 + wid * 32 + i * 16 + l15;
    size_t grow = (size_t)b * 2048 + qabs;
#pragma unroll
    for (int df = 0; df < 4; ++df) {
      int d0 = df * 16 + 4 * g;
      ushort4 gt = *(const ushort4*)&gateb[grow * 2048 + h * 64 + d0];
      float o0 = oaccT[i][df][0] * rl * (1.f / (1.f + __expf(-bf2f(gt.x))));
      float o1 = oaccT[i][df][1] * rl * (1.f / (1.f + __expf(-bf2f(gt.y))));
      float o2 = oaccT[i][df][2] * rl * (1.f / (1.f + __expf(-bf2f(gt.z))));
      float o3 = oaccT[i][df][3] * rl * (1.f / (1.f + __expf(-bf2f(gt.w))));
      *(uint2*)&attng[grow * 2048 + h * 64 + d0] =
          make_uint2(cvt_pk_bf16(o0, o1), cvt_pk_bf16(o2, o3));
    }
  }
}

extern "C" void kernel_launch(void* const* d_in, const int* in_sizes, int n_in,
                              void* d_out, int out_size, void* d_ws, size_t ws_size,
                              hipStream_t stream) {
  const float* hidden = (const float*)d_in[0];
  const float* cosT = (const float*)d_in[1];
  const float* sinT = (const float*)d_in[2];
  const float* wq = (const float*)d_in[4];
  const float* wk = (const float*)d_in[5];
  const float* wo = (const float*)d_in[7];
  char* ws = (char*)d_ws;
  unsigned short* hb16  = (unsigned short*)(ws + 0);          // 4096x2048 bf16
  unsigned short* wcatT = (unsigned short*)(ws + 16777216);   // 4608x2048 bf16
  unsigned short* woT   = (unsigned short*)(ws + 35651584);   // 2048x2048 bf16
  unsigned short* gateb = (unsigned short*)(ws + 44040192);   // [b*2048+s][2048] bf16
  unsigned short* qrope = (unsigned short*)(ws + 60817408);   // [2][32][2048][64] bf16 (log2e-scaled)
  unsigned short* krope = (unsigned short*)(ws + 77594624);   // [2][8][2048][64] bf16
  unsigned short* kTb   = (unsigned short*)(ws + 81788928);   // [2][8][64][2048] bf16
  unsigned short* attng = (unsigned short*)(ws + 85983232);   // 4096x2048 bf16

  conv_bf16<<<dim3(2048), dim3(256), 0, stream>>>(hidden, hb16, 2097152);
  tconv<<<dim3(128, 64), dim3(32, 8), 0, stream>>>(wq, wcatT, 4096, 0, 2048);
  tconv<<<dim3(16, 64), dim3(32, 8), 0, stream>>>(wk, wcatT, 512, 4096, 2048);
  tconv<<<dim3(64, 64), dim3(32, 8), 0, stream>>>(wo, woT, 2048, 0, 2048);
  gemm_qgk<<<dim3(36, 32), dim3(256), 0, stream>>>(hb16, wcatT, cosT, sinT,
                                                   qrope, gateb, krope);
  ktrans<<<dim3(32, 16), dim3(256), 0, stream>>>(krope, kTb);
  attn_fused<<<dim3(64, 16), dim3(256), 0, stream>>>(qrope, krope, kTb, gateb, attng);
  gemm_bt<float><<<dim3(16, 32), dim3(256), 0, stream>>>(attng, woT, (float*)d_out, 4096, 2048, 2048);
}

// Round 12
// 252.180 us; speedup vs baseline: 1.0143x; 1.0143x over previous
//
#include <hip/hip_runtime.h>

typedef float f32x4 __attribute__((ext_vector_type(4)));
typedef short bf16x8 __attribute__((ext_vector_type(8)));

__device__ __forceinline__ float bf2f(unsigned short h) {
  return __uint_as_float(((unsigned int)h) << 16);
}
__device__ __forceinline__ unsigned short f2bf(float f) {
  unsigned int u = __float_as_uint(f);
  unsigned int r = u + 0x7fffu + ((u >> 16) & 1u);
  return (unsigned short)(r >> 16);
}
__device__ __forceinline__ float fast_exp2(float x) {
  return __builtin_amdgcn_exp2f(x);  // v_exp_f32: D = 2^S0
}
__device__ __forceinline__ unsigned cvt_pk_bf16(float lo, float hi) {
  unsigned d;
  asm("v_cvt_pk_bf16_f32 %0, %1, %2" : "=v"(d) : "v"(lo), "v"(hi));
  return d;
}
__device__ __forceinline__ float max3f(float a, float b, float c) {
  float d;
  asm("v_max3_f32 %0, %1, %2, %3" : "=v"(d) : "v"(a), "v"(b), "v"(c));
  return d;
}

__device__ __forceinline__ void gload_lds16(const void* g, void* l) {
  __builtin_amdgcn_global_load_lds((const __attribute__((address_space(1))) void*)g,
                                   (__attribute__((address_space(3))) void*)l, 16, 0, 0);
}

// ---------------- fp32 -> bf16 elementwise convert (vectorized) ----------------
__global__ void conv_bf16(const float* __restrict__ src, unsigned short* __restrict__ dst, int n4) {
  for (int i = blockIdx.x * blockDim.x + threadIdx.x; i < n4; i += gridDim.x * blockDim.x) {
    float4 v = ((const float4*)src)[i];
    ushort4 o;
    o.x = f2bf(v.x); o.y = f2bf(v.y); o.z = f2bf(v.z); o.w = f2bf(v.w);
    ((ushort4*)dst)[i] = o;
  }
}

// ---------------- pack cos/sin fp32 tables into one u32 (bf16 lo=cos, hi=sin) ----------------
__global__ void conv_cs(const float* __restrict__ cosT, const float* __restrict__ sinT,
                        unsigned* __restrict__ cs, int n) {
  int i = blockIdx.x * blockDim.x + threadIdx.x;
  if (i < n) cs[i] = cvt_pk_bf16(cosT[i], sinT[i]);
}

// ------------- fp32 [R][C] -> bf16 dst[C + dstRowOff][R] transpose-convert -------------
__global__ void tconv(const float* __restrict__ src, unsigned short* __restrict__ dst,
                      int C, int dstRowOff, int dstLD) {
  __shared__ float tile[32][33];
  int c0 = blockIdx.x * 32, r0 = blockIdx.y * 32;
  int tx = threadIdx.x, ty = threadIdx.y;
#pragma unroll
  for (int i = 0; i < 4; ++i)
    tile[ty + i * 8][tx] = src[(size_t)(r0 + ty + i * 8) * C + c0 + tx];
  __syncthreads();
#pragma unroll
  for (int i = 0; i < 4; ++i)
    dst[(size_t)(dstRowOff + c0 + ty + i * 8) * dstLD + r0 + tx] = f2bf(tile[tx][ty + i * 8]);
}

// ---------------- generic GEMM: C[M][N] = A * BT^T (bf16 in, fp32/bf16 out) ----------------
template <typename OutT>
__global__ __launch_bounds__(256) void gemm_bt(const unsigned short* __restrict__ A,
                                               const unsigned short* __restrict__ BT,
                                               OutT* __restrict__ C, int M, int N, int K) {
  __shared__ unsigned short As[128 * 64];
  __shared__ unsigned short Bs[128 * 64];
  const int tid = threadIdx.x;
  const int lane = tid & 63;
  const int wid = tid >> 6;
  const int g = lane >> 4, l15 = lane & 15;
  const int wr = wid >> 1, wc = wid & 1;
  const int bm = blockIdx.y, bn = blockIdx.x;
  const unsigned short* Ab = A + (size_t)bm * 128 * K;
  const unsigned short* Bb = BT + (size_t)bn * 128 * K;
  f32x4 acc[4][4] = {};
  int Rj[4], csj[4];
#pragma unroll
  for (int j = 0; j < 4; ++j) {
    int c = j * 256 + tid;
    Rj[j] = c >> 3;
    csj[j] = ((c & 7) ^ (Rj[j] & 7)) * 8;
  }
  for (int k0 = 0; k0 < K; k0 += 64) {
#pragma unroll
    for (int j = 0; j < 4; ++j) {
      gload_lds16(Ab + (size_t)Rj[j] * K + k0 + csj[j], &As[(j * 256 + (wid << 6)) * 8]);
      gload_lds16(Bb + (size_t)Rj[j] * K + k0 + csj[j], &Bs[(j * 256 + (wid << 6)) * 8]);
    }
    __syncthreads();
    bf16x8 af[4][2], bfr[4][2];
#pragma unroll
    for (int i = 0; i < 4; ++i)
#pragma unroll
      for (int kk = 0; kk < 2; ++kk) {
        int rowa = wr * 64 + i * 16 + l15;
        int cha = ((kk * 4 + g) ^ (rowa & 7)) * 8;
        af[i][kk] = *(const bf16x8*)&As[rowa * 64 + cha];
        int rowb = wc * 64 + i * 16 + l15;
        int chb = ((kk * 4 + g) ^ (rowb & 7)) * 8;
        bfr[i][kk] = *(const bf16x8*)&Bs[rowb * 64 + chb];
      }
    __builtin_amdgcn_s_setprio(1);
#pragma unroll
    for (int kk = 0; kk < 2; ++kk)
#pragma unroll
      for (int i = 0; i < 4; ++i)
#pragma unroll
        for (int j = 0; j < 4; ++j)
          acc[i][j] = __builtin_amdgcn_mfma_f32_16x16x32_bf16(af[i][kk], bfr[j][kk], acc[i][j], 0, 0, 0);
    __builtin_amdgcn_s_setprio(0);
    __syncthreads();
  }
  const int rbase = bm * 128 + wr * 64 + ((lane >> 4) << 2);
  const int cbase = bn * 128 + wc * 64 + l15;
#pragma unroll
  for (int i = 0; i < 4; ++i)
#pragma unroll
    for (int j = 0; j < 4; ++j)
#pragma unroll
      for (int r = 0; r < 4; ++r) {
        int row = rbase + i * 16 + r;
        int col = cbase + j * 16;
        if constexpr (sizeof(OutT) == 2)
          C[(size_t)row * N + col] = f2bf(acc[i][j][r]);
        else
          C[(size_t)row * N + col] = acc[i][j][r];
      }
}

// ---------------- GEMM1 with fused RoPE / gate-split epilogue ----------------
// A = hb16 [4096][2048], BT = wcatT [4608][2048]. Cols 0..2047 -> roped q (log2e-scaled,
// head-major); 2048..4095 -> gate buffer; 4096..4607 -> roped k (head-major).
// cs = packed bf16 cos|sin table [2048][64] (one u32 load per (s,d)).
__global__ __launch_bounds__(256) void gemm_qgk(const unsigned short* __restrict__ A,
                                                const unsigned short* __restrict__ BT,
                                                const unsigned* __restrict__ cs,
                                                unsigned short* __restrict__ qrope,
                                                unsigned short* __restrict__ gateb,
                                                unsigned short* __restrict__ krope) {
  const int K = 2048;
  __shared__ unsigned short As[128 * 64];
  __shared__ unsigned short Bs[128 * 64];
  const int tid = threadIdx.x;
  const int lane = tid & 63;
  const int wid = tid >> 6;
  const int g = lane >> 4, l15 = lane & 15;
  const int wr = wid >> 1, wc = wid & 1;
  const int bm = blockIdx.y, bn = blockIdx.x;
  const unsigned short* Ab = A + (size_t)bm * 128 * K;
  const unsigned short* Bb = BT + (size_t)bn * 128 * K;
  f32x4 acc[4][4] = {};
  int Rj[4], csj[4];
#pragma unroll
  for (int j = 0; j < 4; ++j) {
    int c = j * 256 + tid;
    Rj[j] = c >> 3;
    csj[j] = ((c & 7) ^ (Rj[j] & 7)) * 8;
  }
  for (int k0 = 0; k0 < K; k0 += 64) {
#pragma unroll
    for (int j = 0; j < 4; ++j) {
      gload_lds16(Ab + (size_t)Rj[j] * K + k0 + csj[j], &As[(j * 256 + (wid << 6)) * 8]);
      gload_lds16(Bb + (size_t)Rj[j] * K + k0 + csj[j], &Bs[(j * 256 + (wid << 6)) * 8]);
    }
    __syncthreads();
    bf16x8 af[4][2], bfr[4][2];
#pragma unroll
    for (int i = 0; i < 4; ++i)
#pragma unroll
      for (int kk = 0; kk < 2; ++kk) {
        int rowa = wr * 64 + i * 16 + l15;
        int cha = ((kk * 4 + g) ^ (rowa & 7)) * 8;
        af[i][kk] = *(const bf16x8*)&As[rowa * 64 + cha];
        int rowb = wc * 64 + i * 16 + l15;
        int chb = ((kk * 4 + g) ^ (rowb & 7)) * 8;
        bfr[i][kk] = *(const bf16x8*)&Bs[rowb * 64 + chb];
      }
    __builtin_amdgcn_s_setprio(1);
#pragma unroll
    for (int kk = 0; kk < 2; ++kk)
#pragma unroll
      for (int i = 0; i < 4; ++i)
#pragma unroll
        for (int j = 0; j < 4; ++j)
          acc[i][j] = __builtin_amdgcn_mfma_f32_16x16x32_bf16(af[i][kk], bfr[j][kk], acc[i][j], 0, 0, 0);
    __builtin_amdgcn_s_setprio(0);
    __syncthreads();
  }
  const int rbase = bm * 128 + wr * 64 + ((lane >> 4) << 2);
  if (bn < 16) {
    const int h = bn * 2 + wc;
#pragma unroll
    for (int i = 0; i < 4; ++i)
#pragma unroll
      for (int j = 0; j < 4; ++j)
#pragma unroll
        for (int r = 0; r < 4; ++r) {
          int row = rbase + i * 16 + r;
          int b = row >> 11, s = row & 2047;
          int d = j * 16 + l15;
          unsigned csv = cs[s * 64 + d];
          float c = bf2f((unsigned short)(csv & 0xffffu));
          float sn = bf2f((unsigned short)(csv >> 16));
          float x = acc[i][j][r], xp = acc[i][j ^ 2][r];
          float v = x * c + (((j & 2) == 0) ? -xp : xp) * sn;
          qrope[((size_t)(b * 32 + h) * 2048 + s) * 64 + d] = f2bf(v * 1.44269504089f);
        }
  } else if (bn < 32) {
    const int cb = (bn - 16) * 128 + wc * 64;
#pragma unroll
    for (int i = 0; i < 4; ++i)
#pragma unroll
      for (int j = 0; j < 4; ++j)
#pragma unroll
        for (int r = 0; r < 4; ++r) {
          int row = rbase + i * 16 + r;
          int b = row >> 11, s = row & 2047;
          gateb[(size_t)(b * 2048 + s) * 2048 + cb + j * 16 + l15] = f2bf(acc[i][j][r]);
        }
  } else {
    const int kh = (bn - 32) * 2 + wc;
#pragma unroll
    for (int i = 0; i < 4; ++i)
#pragma unroll
      for (int j = 0; j < 4; ++j)
#pragma unroll
        for (int r = 0; r < 4; ++r) {
          int row = rbase + i * 16 + r;
          int b = row >> 11, s = row & 2047;
          int d = j * 16 + l15;
          unsigned csv = cs[s * 64 + d];
          float c = bf2f((unsigned short)(csv & 0xffffu));
          float sn = bf2f((unsigned short)(csv >> 16));
          float x = acc[i][j][r], xp = acc[i][j ^ 2][r];
          float v = x * c + (((j & 2) == 0) ? -xp : xp) * sn;
          krope[((size_t)(b * 8 + kh) * 2048 + s) * 64 + d] = f2bf(v);
        }
  }
}

// ---------------- krope [bh][2048][64] -> kT [bh][64][2048] ----------------
__global__ void ktrans(const unsigned short* __restrict__ krope, unsigned short* __restrict__ kT) {
  __shared__ unsigned short tile[64][65];
  int bh = blockIdx.y;
  int s0 = blockIdx.x * 64;
  const unsigned short* src = krope + (size_t)bh * 2048 * 64;
  unsigned short* dst = kT + (size_t)bh * 64 * 2048;
  int tx = threadIdx.x & 63, ty = threadIdx.x >> 6;
#pragma unroll
  for (int i = 0; i < 16; ++i)
    tile[ty + i * 4][tx] = src[(size_t)(s0 + ty + i * 4) * 64 + tx];
  __syncthreads();
#pragma unroll
  for (int i = 0; i < 16; ++i)
    dst[(size_t)(ty + i * 4) * 2048 + s0 + tx] = tile[tx][ty + i * 4];
}

// ---------------- fused causal flash attention (V == roped K), gated epilogue ----------------
// Round-5 measured structure (92us): Q staged via Ps LDS, grid (bh fastest, qblk=15-y),
// double-buffered K/KT staging, swapped QK^T, exp2+defer-max softmax, single barrier/tile.
// cvt_pk P-write/epilogue + max3 reduction (VALU-only swap, verified rounds 6-10).
__global__ __launch_bounds__(256) void attn_fused(const unsigned short* __restrict__ qrope,
                                                  const unsigned short* __restrict__ krope,
                                                  const unsigned short* __restrict__ kT,
                                                  const unsigned short* __restrict__ gateb,
                                                  unsigned short* __restrict__ attng) {
  __shared__ unsigned short Ks[2][64 * 64];
  __shared__ unsigned short KTs[2][64 * 64];
  __shared__ unsigned short Ps[128 * 64];  // Q staging, then P tiles (wave-private rows)
  const int qblk = 15 - blockIdx.y;       // long blocks dispatched first
  const int bh = blockIdx.x;              // 0..63
  const int b = bh >> 5, h = bh & 31, kh = h >> 2;
  const int q0 = qblk * 128;
  const int tid = threadIdx.x, lane = tid & 63, wid = tid >> 6;
  const int g = lane >> 4, l15 = lane & 15;
  const unsigned short* Qbase = qrope + ((size_t)(b * 32 + h) * 2048 + q0) * 64;
  const unsigned short* Kbase = krope + (size_t)(b * 8 + kh) * 2048 * 64;
  const unsigned short* KTbase = kT + (size_t)(b * 8 + kh) * 64 * 2048;

  // ---- stage Q (16KB) into Ps, swizzled-source / linear-LDS ----
#pragma unroll
  for (int j = 0; j < 4; ++j) {
    int F = ((j * 4 + wid) << 10) + (lane << 4);  // byte offset in tile
    int R = F >> 7;
    int cs = ((F >> 4) & 7) ^ (R & 7);
    gload_lds16(Qbase + (size_t)R * 64 + cs * 8, &Ps[(j * 4 + wid) << 9]);
  }
  // ---- stage K/KT tile 0 into buffer 0 ----
  {
#pragma unroll
    for (int j = 0; j < 2; ++j) {
      int F = ((j * 4 + wid) << 10) + (lane << 4);
      int R = F >> 7;
      int cs = ((F >> 4) & 7) ^ (R & 7);
      gload_lds16(Kbase + (size_t)R * 64 + cs * 8, &Ks[0][(j * 4 + wid) << 9]);
      gload_lds16(KTbase + (size_t)R * 2048 + cs * 8, &KTs[0][(j * 4 + wid) << 9]);
    }
  }
  __syncthreads();

  // ---- Q fragments (swizzled read) ----
  bf16x8 qf[2][2];
#pragma unroll
  for (int i = 0; i < 2; ++i)
#pragma unroll
    for (int ks = 0; ks < 2; ++ks) {
      int row = wid * 32 + i * 16 + l15;
      int ch = (ks * 4 + g) ^ (row & 7);
      qf[i][ks] = *(const bf16x8*)&Ps[row * 64 + ch * 8];
    }
  __syncthreads();  // all waves have Q; Ps reusable

  f32x4 oaccT[2][4] = {};
  float mrow[2] = {-1e30f, -1e30f}, lrow[2] = {0.f, 0.f};

  const int nt = 2 * qblk + 2;
  for (int t = 0; t < nt; ++t) {
    const int cur = t & 1;
    if (t + 1 < nt) {
      const int nb = cur ^ 1;
#pragma unroll
      for (int j = 0; j < 2; ++j) {
        int F = ((j * 4 + wid) << 10) + (lane << 4);
        int R = F >> 7;
        int cs = ((F >> 4) & 7) ^ (R & 7);
        gload_lds16(Kbase + (size_t)((t + 1) * 64 + R) * 64 + cs * 8, &Ks[nb][(j * 4 + wid) << 9]);
        gload_lds16(KTbase + (size_t)R * 2048 + (t + 1) * 64 + cs * 8, &KTs[nb][(j * 4 + wid) << 9]);
      }
    }
    // ---- S^T = K * Q^T  (rows = keys, cols = q); S in log2 units (Q pre-scaled) ----
    f32x4 st[2][4] = {};
#pragma unroll
    for (int ks = 0; ks < 2; ++ks) {
      bf16x8 kf[4];
#pragma unroll
      for (int nf = 0; nf < 4; ++nf) {
        int row = nf * 16 + l15;
        int ch = (ks * 4 + g) ^ (row & 7);
        kf[nf] = *(const bf16x8*)&Ks[cur][row * 64 + ch * 8];
      }
      __builtin_amdgcn_s_setprio(1);
#pragma unroll
      for (int i = 0; i < 2; ++i)
#pragma unroll
        for (int nf = 0; nf < 4; ++nf)
          st[i][nf] = __builtin_amdgcn_mfma_f32_16x16x32_bf16(kf[nf], qf[i][ks], st[i][nf], 0, 0, 0);
      __builtin_amdgcn_s_setprio(0);
    }
    if (t >= 2 * qblk) {
#pragma unroll
      for (int i = 0; i < 2; ++i) {
        int qabs = q0 + wid * 32 + i * 16 + l15;
#pragma unroll
        for (int nf = 0; nf < 4; ++nf)
#pragma unroll
          for (int r = 0; r < 4; ++r) {
            int kabs = t * 64 + nf * 16 + 4 * g + r;
            if (kabs > qabs) st[i][nf][r] += -1e9f;
          }
      }
    }
    // ---- online softmax, exp2 domain, defer-max, max3 tree ----
#pragma unroll
    for (int i = 0; i < 2; ++i) {
      float a0 = max3f(st[i][0][0], st[i][0][1], st[i][0][2]);
      float a1 = max3f(st[i][0][3], st[i][1][0], st[i][1][1]);
      float a2 = max3f(st[i][1][2], st[i][1][3], st[i][2][0]);
      float a3 = max3f(st[i][2][1], st[i][2][2], st[i][2][3]);
      float a4 = max3f(st[i][3][0], st[i][3][1], st[i][3][2]);
      float pm = fmaxf(max3f(a0, a1, a2), max3f(a3, a4, st[i][3][3]));
      pm = fmaxf(pm, __shfl_xor(pm, 16, 64));
      pm = fmaxf(pm, __shfl_xor(pm, 32, 64));
      if (!__all(pm <= mrow[i] + 8.f)) {
        float mnew = fmaxf(mrow[i], pm);
        float scale = fast_exp2(mrow[i] - mnew);
        mrow[i] = mnew;
        lrow[i] *= scale;
#pragma unroll
        for (int df = 0; df < 4; ++df)
#pragma unroll
          for (int r = 0; r < 4; ++r) oaccT[i][df][r] *= scale;
      }
      float rs = 0.f;
#pragma unroll
      for (int nf = 0; nf < 4; ++nf)
#pragma unroll
        for (int r = 0; r < 4; ++r) {
          float p = fast_exp2(st[i][nf][r] - mrow[i]);
          st[i][nf][r] = p;
          rs += p;
        }
      rs += __shfl_xor(rs, 16, 64);
      rs += __shfl_xor(rs, 32, 64);
      lrow[i] += rs;
    }
    // ---- write P rows (wave-private; hw cvt_pk, 8B stores) ----
#pragma unroll
    for (int i = 0; i < 2; ++i) {
      int q = wid * 32 + i * 16 + l15;
#pragma unroll
      for (int nf = 0; nf < 4; ++nf) {
        int k0 = nf * 16 + 4 * g;
        int ch = (k0 >> 3) ^ (q & 7);
        unsigned w0 = cvt_pk_bf16(st[i][nf][0], st[i][nf][1]);
        unsigned w1 = cvt_pk_bf16(st[i][nf][2], st[i][nf][3]);
        *(uint2*)&Ps[q * 64 + ch * 8 + (k0 & 7)] = make_uint2(w0, w1);
      }
    }
    // no barrier: P rows are read only by the writing wave
    // ---- O^T += V^T * P^T  (rows = d, cols = q) ----
#pragma unroll
    for (int ks = 0; ks < 2; ++ks) {
      bf16x8 pf[2], vf[4];
#pragma unroll
      for (int i = 0; i < 2; ++i) {
        int row = wid * 32 + i * 16 + l15;
        int ch = (ks * 4 + g) ^ (row & 7);
        pf[i] = *(const bf16x8*)&Ps[row * 64 + ch * 8];
      }
#pragma unroll
      for (int df = 0; df < 4; ++df) {
        int row = df * 16 + l15;
        int ch = (ks * 4 + g) ^ (row & 7);
        vf[df] = *(const bf16x8*)&KTs[cur][row * 64 + ch * 8];
      }
      __builtin_amdgcn_s_setprio(1);
#pragma unroll
      for (int i = 0; i < 2; ++i)
#pragma unroll
        for (int df = 0; df < 4; ++df)
          oaccT[i][df] = __builtin_amdgcn_mfma_f32_16x16x32_bf16(vf[df], pf[i], oaccT[i][df], 0, 0, 0);
      __builtin_amdgcn_s_setprio(0);
    }
    __syncthreads();  // staging buffers for t+1 may now be overwritten
  }
  // ---- gated epilogue (O^T: lane holds q = lane&15, d = df*16 + 4g + r) ----
#pragma unroll
  for (int i = 0; i < 2; ++i) {
    float rl = 1.f / lrow[i];
    int qabs = q0 + wid * 32 + i * 16 + l15;
    size_t grow = (size_t)b * 2048 + qabs;
#pragma unroll
    for (int df = 0; df < 4; ++df) {
      int d0 = df * 16 + 4 * g;
      ushort4 gt = *(const ushort4*)&gateb[grow * 2048 + h * 64 + d0];
      float o0 = oaccT[i][df][0] * rl * (1.f / (1.f + __expf(-bf2f(gt.x))));
      float o1 = oaccT[i][df][1] * rl * (1.f / (1.f + __expf(-bf2f(gt.y))));
      float o2 = oaccT[i][df][2] * rl * (1.f / (1.f + __expf(-bf2f(gt.z))));
      float o3 = oaccT[i][df][3] * rl * (1.f / (1.f + __expf(-bf2f(gt.w))));
      *(uint2*)&attng[grow * 2048 + h * 64 + d0] =
          make_uint2(cvt_pk_bf16(o0, o1), cvt_pk_bf16(o2, o3));
    }
  }
}

extern "C" void kernel_launch(void* const* d_in, const int* in_sizes, int n_in,
                              void* d_out, int out_size, void* d_ws, size_t ws_size,
                              hipStream_t stream) {
  const float* hidden = (const float*)d_in[0];
  const float* cosT = (const float*)d_in[1];
  const float* sinT = (const float*)d_in[2];
  const float* wq = (const float*)d_in[4];
  const float* wk = (const float*)d_in[5];
  const float* wo = (const float*)d_in[7];
  char* ws = (char*)d_ws;
  unsigned short* hb16  = (unsigned short*)(ws + 0);          // 4096x2048 bf16
  unsigned short* wcatT = (unsigned short*)(ws + 16777216);   // 4608x2048 bf16
  unsigned short* woT   = (unsigned short*)(ws + 35651584);   // 2048x2048 bf16
  unsigned short* gateb = (unsigned short*)(ws + 44040192);   // [b*2048+s][2048] bf16
  unsigned short* qrope = (unsigned short*)(ws + 60817408);   // [2][32][2048][64] bf16 (log2e-scaled)
  unsigned short* krope = (unsigned short*)(ws + 77594624);   // [2][8][2048][64] bf16
  unsigned short* kTb   = (unsigned short*)(ws + 81788928);   // [2][8][64][2048] bf16
  unsigned short* attng = (unsigned short*)(ws + 85983232);   // 4096x2048 bf16
  unsigned*       csT   = (unsigned*)(ws + 102760448);        // [2048][64] packed bf16 cos|sin

  conv_bf16<<<dim3(2048), dim3(256), 0, stream>>>(hidden, hb16, 2097152);
  conv_cs<<<dim3(512), dim3(256), 0, stream>>>(cosT, sinT, csT, 131072);
  tconv<<<dim3(128, 64), dim3(32, 8), 0, stream>>>(wq, wcatT, 4096, 0, 2048);
  tconv<<<dim3(16, 64), dim3(32, 8), 0, stream>>>(wk, wcatT, 512, 4096, 2048);
  tconv<<<dim3(64, 64), dim3(32, 8), 0, stream>>>(wo, woT, 2048, 0, 2048);
  gemm_qgk<<<dim3(36, 32), dim3(256), 0, stream>>>(hb16, wcatT, csT,
                                                   qrope, gateb, krope);
  ktrans<<<dim3(32, 16), dim3(256), 0, stream>>>(krope, kTb);
  attn_fused<<<dim3(64, 16), dim3(256), 0, stream>>>(qrope, krope, kTb, gateb, attng);
  gemm_bt<float><<<dim3(16, 32), dim3(256), 0, stream>>>(attng, woT, (float*)d_out, 4096, 2048, 2048);
}